// Round 5
// baseline (2772.288 us; speedup 1.0000x reference)
//
#include <hip/hip_runtime.h>
#include <cstdint>

typedef __attribute__((ext_vector_type(8))) _Float16 f16x8;
typedef __attribute__((ext_vector_type(4))) float f32x4;

#define SEQL 256

// ws byte offsets (prep output; identical layout to prior rounds)
#define WS_B0H   0        // [3 kstep][16 ntile][64 lane][8] f16 = 49152 B
#define WS_B0L   49152    // lo pre-scaled x2048
#define WS_B1H   98304    // [4][16][64][8] f16 hi = 65536 B, then lo contiguous
#define WS_BIAS0 229376   // 256 f32, index = cell*4+gate, pre-scaled
#define WS_BIAS1 230400

// LDS: h-exchange only. 16 rows (batch cols) x 528 B; rows 8-15 stay ZERO
// (this block only populates 8 batch cols; MFMA cols 8-15 read zeros).
// byte offs in row: h1_0@0(128B) h1_1@128 h2_0@256 h2_1@384 pad@512
#define ASTR 528
#define L_HD 8448         // head exchange: 8 rows x 272 B
#define HDSTR 272
#define LDS_TOTAL 12800

#define NEG_L   -1.4426950408889634f   // -log2(e)
#define NEG_2L  -2.8853900817779268f   // -2*log2(e)
#define LO_SCALE 2048.0f
#define LO_INV   4.8828125e-4f         // 1/2048

__device__ __forceinline__ float ex2(float x) { return __builtin_amdgcn_exp2f(x); }
__device__ __forceinline__ float rcp_(float x) { return __builtin_amdgcn_rcpf(x); }
__device__ __forceinline__ f32x4 mfma16(f16x8 a, f16x8 b, f32x4 c) {
  return __builtin_amdgcn_mfma_f32_16x16x32_f16(a, b, c, 0, 0, 0);
}
__device__ __forceinline__ f16x8 zero8() {
  f16x8 z;
#pragma unroll
  for (int i = 0; i < 8; ++i) z[i] = (_Float16)0.f;
  return z;
}
__device__ __forceinline__ f16x8 cvt8(f32x4 a, f32x4 b) {
  f16x8 r;
#pragma unroll
  for (int j = 0; j < 4; ++j) r[j] = (_Float16)a[j];
#pragma unroll
  for (int j = 0; j < 4; ++j) r[4 + j] = (_Float16)b[j];
  return r;
}

// Pack weights into MFMA fragment order (A/B f16 fragment layouts are
// identical on gfx950), f16 hi + f16 lo(x2048) split, pre-scaled by
// -log2e (i,f,o) / -2log2e (g). UNCHANGED from prior rounds.
__global__ __launch_bounds__(256) void prep(
    const float* __restrict__ Wih0, const float* __restrict__ Whh0,
    const float* __restrict__ bih0, const float* __restrict__ bhh0,
    const float* __restrict__ Wih1, const float* __restrict__ Whh1,
    const float* __restrict__ bih1, const float* __restrict__ bhh1,
    unsigned char* __restrict__ ws) {
  int e = blockIdx.x * 256 + threadIdx.x;
  if (e < 24576) {  // B0: K=96 = [x(32)|h1(64)]
    int j = e & 7, lane = (e >> 3) & 63, nt = (e >> 9) & 15, ks = e >> 13;
    int kdim = ks * 32 + (lane >> 4) * 8 + j;
    int col = nt * 16 + (lane & 15);   // gate-row index of the A-operand
    int ko = col >> 2, g = col & 3;
    float w = (kdim < 32) ? Wih0[(g * 64 + ko) * 32 + kdim]
                          : Whh0[(g * 64 + ko) * 64 + (kdim - 32)];
    w *= (g == 2) ? NEG_2L : NEG_L;
    _Float16 hi = (_Float16)w;
    _Float16 lo = (_Float16)((w - (float)hi) * LO_SCALE);
    ((_Float16*)(ws + WS_B0H))[e] = hi;
    ((_Float16*)(ws + WS_B0L))[e] = lo;
  } else if (e < 57344) {  // B1: K=128 = [h1(64)|h2(64)]
    int r = e - 24576;
    int j = r & 7, lane = (r >> 3) & 63, nt = (r >> 9) & 15, ks = r >> 13;
    int kdim = ks * 32 + (lane >> 4) * 8 + j;
    int col = nt * 16 + (lane & 15);
    int ko = col >> 2, g = col & 3;
    float w = (kdim < 64) ? Wih1[(g * 64 + ko) * 64 + kdim]
                          : Whh1[(g * 64 + ko) * 64 + (kdim - 64)];
    w *= (g == 2) ? NEG_2L : NEG_L;
    _Float16 hi = (_Float16)w;
    _Float16 lo = (_Float16)((w - (float)hi) * LO_SCALE);
    ((_Float16*)(ws + WS_B1H))[r] = hi;
    ((_Float16*)(ws + WS_B1H + 65536))[r] = lo;
  } else if (e < 57856) {  // biases (pre-scaled, fp32)
    int r = e - 57344;
    int col = r & 255, ko = col >> 2, g = col & 3;
    float v = (r < 256) ? bih0[g * 64 + ko] + bhh0[g * 64 + ko]
                        : bih1[g * 64 + ko] + bhh1[g * 64 + ko];
    v *= (g == 2) ? NEG_2L : NEG_L;
    ((float*)(ws + (r < 256 ? WS_BIAS0 : WS_BIAS1)))[col] = v;
  }
}

// v10: v9 structure (8 waves x 2 ntiles, x direct-from-global, single
// barrier) but 8 batch/block x 512 blocks -> 2 blocks/CU with INDEPENDENT
// barriers: block B's waves fill block A's lgkm/barrier/cell-chain stalls.
// MFMA tiles half-empty in N (cost: 2x MFMA instr/CU, absorbed by the 31%-
// utilized matrix pipe); cells/trans per CU conserved (masked to mcol<8).
__global__ __launch_bounds__(512, 4) void lstm_mfma10(
    const float* __restrict__ x, const unsigned char* __restrict__ ws,
    const float* __restrict__ W1, const float* __restrict__ b1,
    const float* __restrict__ W2, const float* __restrict__ b2,
    float* __restrict__ out) {
  __shared__ __align__(16) unsigned char lds[LDS_TOTAL];
  const int tid = threadIdx.x;
  const int lane = tid & 63, wave = tid >> 6;  // 8 waves, ntiles {wave, wave+8}
  const int q = lane >> 4, mcol = lane & 15;
  const bool act = mcol < 8;                   // lanes with a real batch col

  // ---- Weight fragments -> registers (loop-invariant; A-operand) ----
  f16x8 w0h[2][3], w0l[2][3], w1h[2][4], w1l[2][4];
#pragma unroll
  for (int m = 0; m < 2; ++m) {
    const int nt = wave + 8 * m;
#pragma unroll
    for (int ks = 0; ks < 3; ++ks) {
      int rec = (ks * 16 + nt) * 64 + lane;
      w0h[m][ks] = ((const f16x8*)(ws + WS_B0H))[rec];
      w0l[m][ks] = ((const f16x8*)(ws + WS_B0L))[rec];
    }
#pragma unroll
    for (int ks = 0; ks < 4; ++ks) {
      int rec = (ks * 16 + nt) * 64 + lane;
      w1h[m][ks] = ((const f16x8*)(ws + WS_B1H))[rec];
      w1l[m][ks] = ((const f16x8*)(ws + WS_B1H + 65536))[rec];
    }
  }
  // Per-lane bias: gates i,f,g,o of cell 4*nt+q
  f32x4 b0v[2], b1v[2];
#pragma unroll
  for (int m = 0; m < 2; ++m) {
    b0v[m] = ((const f32x4*)(ws + WS_BIAS0))[4 * (wave + 8 * m) + q];
    b1v[m] = ((const f32x4*)(ws + WS_BIAS1))[4 * (wave + 8 * m) + q];
  }
  f32x4 z4;
  z4[0] = z4[1] = z4[2] = z4[3] = 0.f;

  // Zero h-exchange (8448 B = 2112 words). Rows 8-15 must stay zero.
  for (int i = tid; i < 2112; i += 512) ((unsigned*)lds)[i] = 0u;

  // x: active lane (q,mcol<8) owns batch (blockIdx*8+mcol), dims 8q..8q+7.
  // Inactive lanes alias batch (mcol&7) — harmless finite data, L1-cached.
  const float* xp =
      x + (size_t)(blockIdx.x * 8 + (mcol & 7)) * (SEQL * 32) + q * 8;
  f32x4 x0a = *(const f32x4*)(xp);
  f32x4 x0b = *(const f32x4*)(xp + 4);
  f16x8 ax = cvt8(x0a, x0b);             // x(0)
  f32x4 xna = *(const f32x4*)(xp + 32);  // x(1) in flight
  f32x4 xnb = *(const f32x4*)(xp + 36);

  const int ard = mcol * ASTR + q * 16;                  // fragment read base
  const int wr0 = mcol * ASTR + (4 * wave + q) * 2;      // h write, ntile0 cell
  const int wr1 = mcol * ASTR + (4 * wave + 32 + q) * 2; // h write, ntile1 cell

  float c1[2] = {0.f, 0.f}, c2[2] = {0.f, 0.f};
  f16x8 ah1[2], ah2[2];
  ah1[0] = ah1[1] = ah2[0] = ah2[1] = zero8();
  __syncthreads();

  // sigma = rcp(1+2^v); tanh = 2*rcp(1+2^v)-1 (weights pre-scaled).
  auto cell = [&](const f32x4& aH, const f32x4& aL, float& c) -> float {
    float p0 = fmaf(aL[0], LO_INV, aH[0]);
    float p1 = fmaf(aL[1], LO_INV, aH[1]);
    float p2 = fmaf(aL[2], LO_INV, aH[2]);
    float p3 = fmaf(aL[3], LO_INV, aH[3]);
    float gi = rcp_(1.f + ex2(p0));
    float gf = rcp_(1.f + ex2(p1));
    float gg = fmaf(2.f, rcp_(1.f + ex2(p2)), -1.f);
    float go = rcp_(1.f + ex2(p3));
    c = fmaf(gf, c, gi * gg);
    float tc = fmaf(2.f, rcp_(1.f + ex2(c * NEG_2L)), -1.f);
    return go * tc;
  };

  // Interval t: G0 = bias0 + W0@[x(t)|h1(t-1)]; G1 = bias1 + W1@[h1(t-1)|h2(t-2)]
  auto iter = [&](int t, int par, bool doL2) {
    const int h1s = par * 128;         // h1(t) slot
    const int h2s = 256 + par * 128;   // h2(t-1) slot
    f32x4 aH0[2], aL0[2], aH1[2], aL1[2];
    // register-only (ax) first: covers post-barrier ds_read latency
    aH0[0] = mfma16(w0h[0][0], ax, b0v[0]);
    aH0[1] = mfma16(w0h[1][0], ax, b0v[1]);
    aL0[0] = mfma16(w0l[0][0], ax, z4);
    aL0[1] = mfma16(w0l[1][0], ax, z4);
    // ah1[0]-dependent
    aH1[0] = mfma16(w1h[0][0], ah1[0], b1v[0]);
    aH1[1] = mfma16(w1h[1][0], ah1[0], b1v[1]);
    aL1[0] = mfma16(w1l[0][0], ah1[0], z4);
    aL1[1] = mfma16(w1l[1][0], ah1[0], z4);
    aH0[0] = mfma16(w0h[0][1], ah1[0], aH0[0]);
    aH0[1] = mfma16(w0h[1][1], ah1[0], aH0[1]);
    aL0[0] = mfma16(w0l[0][1], ah1[0], aL0[0]);
    aL0[1] = mfma16(w0l[1][1], ah1[0], aL0[1]);
    // ah1[1]-dependent
    aH0[0] = mfma16(w0h[0][2], ah1[1], aH0[0]);
    aH0[1] = mfma16(w0h[1][2], ah1[1], aH0[1]);
    aL0[0] = mfma16(w0l[0][2], ah1[1], aL0[0]);
    aL0[1] = mfma16(w0l[1][2], ah1[1], aL0[1]);
    aH1[0] = mfma16(w1h[0][1], ah1[1], aH1[0]);
    aH1[1] = mfma16(w1h[1][1], ah1[1], aH1[1]);
    aL1[0] = mfma16(w1l[0][1], ah1[1], aL1[0]);
    aL1[1] = mfma16(w1l[1][1], ah1[1], aL1[1]);
    // ah2-dependent
    aH1[0] = mfma16(w1h[0][2], ah2[0], aH1[0]);
    aH1[1] = mfma16(w1h[1][2], ah2[0], aH1[1]);
    aL1[0] = mfma16(w1l[0][2], ah2[0], aL1[0]);
    aL1[1] = mfma16(w1l[1][2], ah2[0], aL1[1]);
    aH1[0] = mfma16(w1h[0][3], ah2[1], aH1[0]);
    aH1[1] = mfma16(w1h[1][3], ah2[1], aH1[1]);
    aL1[0] = mfma16(w1l[0][3], ah2[1], aL1[0]);
    aL1[1] = mfma16(w1l[1][3], ah2[1], aL1[1]);
    // Cells (2 per layer per lane); only active lanes publish h
    float h10 = cell(aH0[0], aL0[0], c1[0]);
    float h11 = cell(aH0[1], aL0[1], c1[1]);
    if (act) {
      *(_Float16*)(lds + wr0 + h1s) = (_Float16)h10;
      *(_Float16*)(lds + wr1 + h1s) = (_Float16)h11;
    }
    if (doL2) {
      float h20 = cell(aH1[0], aL1[0], c2[0]);
      float h21 = cell(aH1[1], aL1[1], c2[1]);
      if (act) {
        *(_Float16*)(lds + wr0 + h2s) = (_Float16)h20;
        *(_Float16*)(lds + wr1 + h2s) = (_Float16)h21;
      }
    }
    // x pipeline: consume loads issued one interval ago, issue next
    ax = cvt8(xna, xnb);               // x(t+1)
    int tn = t + 2; if (tn > SEQL - 1) tn = SEQL - 1;
    xna = *(const f32x4*)(xp + tn * 32);
    xnb = *(const f32x4*)(xp + tn * 32 + 4);
    __syncthreads();  // the ONLY barrier per step
    // Reads for t+1 (WAR vs next interval's writes separated by next barrier)
    ah1[0] = *(const f16x8*)(lds + ard + h1s);
    ah1[1] = *(const f16x8*)(lds + ard + h1s + 64);
    ah2[0] = *(const f16x8*)(lds + ard + h2s);
    ah2[1] = *(const f16x8*)(lds + ard + h2s + 64);
  };

  iter(0, 0, false);  // L1(0) only; h2 slot stays zero => h2(-1)=0
#pragma unroll 1
  for (int tp = 0; tp < 127; ++tp) {
    iter(2 * tp + 1, 1, true);
    iter(2 * tp + 2, 0, true);
  }
  iter(255, 1, true);  // L1(255) + L2(254); bottom reads h1(255), h2(254)

  // ---- Epilogue: L2(255) from registers ----
  {
    f32x4 aH[2], aL[2];
    aH[0] = mfma16(w1h[0][0], ah1[0], b1v[0]);
    aH[1] = mfma16(w1h[1][0], ah1[0], b1v[1]);
    aL[0] = mfma16(w1l[0][0], ah1[0], z4);
    aL[1] = mfma16(w1l[1][0], ah1[0], z4);
    aH[0] = mfma16(w1h[0][1], ah1[1], aH[0]);
    aH[1] = mfma16(w1h[1][1], ah1[1], aH[1]);
    aL[0] = mfma16(w1l[0][1], ah1[1], aL[0]);
    aL[1] = mfma16(w1l[1][1], ah1[1], aL[1]);
    aH[0] = mfma16(w1h[0][2], ah2[0], aH[0]);
    aH[1] = mfma16(w1h[1][2], ah2[0], aH[1]);
    aL[0] = mfma16(w1l[0][2], ah2[0], aL[0]);
    aL[1] = mfma16(w1l[1][2], ah2[0], aL[1]);
    aH[0] = mfma16(w1h[0][3], ah2[1], aH[0]);
    aH[1] = mfma16(w1h[1][3], ah2[1], aH[1]);
    aL[0] = mfma16(w1l[0][3], ah2[1], aL[0]);
    aL[1] = mfma16(w1l[1][3], ah2[1], aL[1]);
    float h20 = cell(aH[0], aL[0], c2[0]);
    float h21 = cell(aH[1], aL[1], c2[1]);
    if (act) {
      *(float*)(lds + L_HD + mcol * HDSTR + (4 * wave + q) * 4) = h20;
      *(float*)(lds + L_HD + mcol * HDSTR + (4 * wave + 32 + q) * 4) = h21;
    }
  }
  __syncthreads();

  // ---- Head: f = relu(h2 @ W1.T + b1); out = f @ W2.T + b2 (fp32 h2) ----
  if (tid < 128) {  // 8 outputs per block
    const int s = tid & 15, bo = tid >> 4;
    const float* h2row = (const float*)(lds + L_HD + bo * HDSTR);
    float partial = 0.f;
#pragma unroll
    for (int kk4 = 0; kk4 < 4; ++kk4) {
      int kk = s * 4 + kk4;
      float f = b1[kk];
#pragma unroll
      for (int j = 0; j < 64; j += 4) {
        f32x4 w = *(const f32x4*)(W1 + kk * 64 + j);
        f = fmaf(w[0], h2row[j], f);
        f = fmaf(w[1], h2row[j + 1], f);
        f = fmaf(w[2], h2row[j + 2], f);
        f = fmaf(w[3], h2row[j + 3], f);
      }
      f = fmaxf(f, 0.f);
      partial = fmaf(f, W2[kk], partial);
    }
    partial += __shfl_xor(partial, 8, 64);
    partial += __shfl_xor(partial, 4, 64);
    partial += __shfl_xor(partial, 2, 64);
    partial += __shfl_xor(partial, 1, 64);
    if (s == 0) out[blockIdx.x * 8 + bo] = partial + b2[0];
  }
}

extern "C" void kernel_launch(void* const* d_in, const int* in_sizes, int n_in,
                              void* d_out, int out_size, void* d_ws, size_t ws_size,
                              hipStream_t stream) {
  const float* x    = (const float*)d_in[0];
  const float* Wih0 = (const float*)d_in[1];
  const float* Whh0 = (const float*)d_in[2];
  const float* bih0 = (const float*)d_in[3];
  const float* bhh0 = (const float*)d_in[4];
  const float* Wih1 = (const float*)d_in[5];
  const float* Whh1 = (const float*)d_in[6];
  const float* bih1 = (const float*)d_in[7];
  const float* bhh1 = (const float*)d_in[8];
  const float* W1   = (const float*)d_in[9];
  const float* b1   = (const float*)d_in[10];
  const float* W2   = (const float*)d_in[11];
  const float* b2   = (const float*)d_in[12];
  unsigned char* ws = (unsigned char*)d_ws;
  float* out = (float*)d_out;

  prep<<<(57856 + 255) / 256, 256, 0, stream>>>(Wih0, Whh0, bih0, bhh0,
                                                Wih1, Whh1, bih1, bhh1, ws);
  lstm_mfma10<<<512, 512, 0, stream>>>(x, ws, W1, b1, W2, b2, out);
}

// Round 6
// 657.688 us; speedup vs baseline: 4.2152x; 4.2152x over previous
//
#include <hip/hip_runtime.h>
#include <cstdint>

typedef __attribute__((ext_vector_type(8))) _Float16 f16x8;
typedef __attribute__((ext_vector_type(4))) float f32x4;

#define SEQL 256

// ws byte offsets (prep output; identical layout to prior rounds)
#define WS_B0H   0        // [3 kstep][16 ntile][64 lane][8] f16 = 49152 B
#define WS_B0L   49152    // lo pre-scaled x2048
#define WS_B1H   98304    // [4][16][64][8] f16 hi = 65536 B, then lo contiguous
#define WS_BIAS0 229376   // 256 f32, index = cell*4+gate, pre-scaled
#define WS_BIAS1 230400

// LDS: h-exchange only. 16 rows (batch cols) x 528 B; rows 8-15 stay ZERO
// (this block only populates 8 batch cols; MFMA cols 8-15 read zeros).
// byte offs in row: h1_0@0(128B) h1_1@128 h2_0@256 h2_1@384 pad@512
#define ASTR 528
#define L_HD 8448         // head exchange: 8 rows x 272 B
#define HDSTR 272
#define LDS_TOTAL 12800

#define NEG_L   -1.4426950408889634f   // -log2(e)
#define NEG_2L  -2.8853900817779268f   // -2*log2(e)
#define LO_SCALE 2048.0f
#define LO_INV   4.8828125e-4f         // 1/2048

__device__ __forceinline__ float ex2(float x) { return __builtin_amdgcn_exp2f(x); }
__device__ __forceinline__ float rcp_(float x) { return __builtin_amdgcn_rcpf(x); }
__device__ __forceinline__ f32x4 mfma16(f16x8 a, f16x8 b, f32x4 c) {
  return __builtin_amdgcn_mfma_f32_16x16x32_f16(a, b, c, 0, 0, 0);
}
__device__ __forceinline__ f16x8 zero8() {
  f16x8 z;
#pragma unroll
  for (int i = 0; i < 8; ++i) z[i] = (_Float16)0.f;
  return z;
}
__device__ __forceinline__ f16x8 cvt8(f32x4 a, f32x4 b) {
  f16x8 r;
#pragma unroll
  for (int j = 0; j < 4; ++j) r[j] = (_Float16)a[j];
#pragma unroll
  for (int j = 0; j < 4; ++j) r[4 + j] = (_Float16)b[j];
  return r;
}

// Pack weights into MFMA fragment order (A/B f16 fragment layouts are
// identical on gfx950), f16 hi + f16 lo(x2048) split, pre-scaled by
// -log2e (i,f,o) / -2log2e (g). UNCHANGED from prior rounds.
__global__ __launch_bounds__(256) void prep(
    const float* __restrict__ Wih0, const float* __restrict__ Whh0,
    const float* __restrict__ bih0, const float* __restrict__ bhh0,
    const float* __restrict__ Wih1, const float* __restrict__ Whh1,
    const float* __restrict__ bih1, const float* __restrict__ bhh1,
    unsigned char* __restrict__ ws) {
  int e = blockIdx.x * 256 + threadIdx.x;
  if (e < 24576) {  // B0: K=96 = [x(32)|h1(64)]
    int j = e & 7, lane = (e >> 3) & 63, nt = (e >> 9) & 15, ks = e >> 13;
    int kdim = ks * 32 + (lane >> 4) * 8 + j;
    int col = nt * 16 + (lane & 15);   // gate-row index of the A-operand
    int ko = col >> 2, g = col & 3;
    float w = (kdim < 32) ? Wih0[(g * 64 + ko) * 32 + kdim]
                          : Whh0[(g * 64 + ko) * 64 + (kdim - 32)];
    w *= (g == 2) ? NEG_2L : NEG_L;
    _Float16 hi = (_Float16)w;
    _Float16 lo = (_Float16)((w - (float)hi) * LO_SCALE);
    ((_Float16*)(ws + WS_B0H))[e] = hi;
    ((_Float16*)(ws + WS_B0L))[e] = lo;
  } else if (e < 57344) {  // B1: K=128 = [h1(64)|h2(64)]
    int r = e - 24576;
    int j = r & 7, lane = (r >> 3) & 63, nt = (r >> 9) & 15, ks = r >> 13;
    int kdim = ks * 32 + (lane >> 4) * 8 + j;
    int col = nt * 16 + (lane & 15);
    int ko = col >> 2, g = col & 3;
    float w = (kdim < 64) ? Wih1[(g * 64 + ko) * 64 + kdim]
                          : Whh1[(g * 64 + ko) * 64 + (kdim - 64)];
    w *= (g == 2) ? NEG_2L : NEG_L;
    _Float16 hi = (_Float16)w;
    _Float16 lo = (_Float16)((w - (float)hi) * LO_SCALE);
    ((_Float16*)(ws + WS_B1H))[r] = hi;
    ((_Float16*)(ws + WS_B1H + 65536))[r] = lo;
  } else if (e < 57856) {  // biases (pre-scaled, fp32)
    int r = e - 57344;
    int col = r & 255, ko = col >> 2, g = col & 3;
    float v = (r < 256) ? bih0[g * 64 + ko] + bhh0[g * 64 + ko]
                        : bih1[g * 64 + ko] + bhh1[g * 64 + ko];
    v *= (g == 2) ? NEG_2L : NEG_L;
    ((float*)(ws + (r < 256 ? WS_BIAS0 : WS_BIAS1)))[col] = v;
  }
}

// v11 = v10 grid (8 batch/block x 512 blocks -> 2 independent barrier
// domains per CU) + v9 launch bounds (512,2): reg-cap 128 so the 112-VGPR
// weight-resident allocation survives (v10's (512,4) capped at 64 VGPR and
// spilled the whole weight set to scratch -> 9.9 GB HBM traffic).
__global__ __launch_bounds__(512, 2) void lstm_mfma11(
    const float* __restrict__ x, const unsigned char* __restrict__ ws,
    const float* __restrict__ W1, const float* __restrict__ b1,
    const float* __restrict__ W2, const float* __restrict__ b2,
    float* __restrict__ out) {
  __shared__ __align__(16) unsigned char lds[LDS_TOTAL];
  const int tid = threadIdx.x;
  const int lane = tid & 63, wave = tid >> 6;  // 8 waves, ntiles {wave, wave+8}
  const int q = lane >> 4, mcol = lane & 15;
  const bool act = mcol < 8;                   // lanes with a real batch col

  // ---- Weight fragments -> registers (loop-invariant; A-operand) ----
  f16x8 w0h[2][3], w0l[2][3], w1h[2][4], w1l[2][4];
#pragma unroll
  for (int m = 0; m < 2; ++m) {
    const int nt = wave + 8 * m;
#pragma unroll
    for (int ks = 0; ks < 3; ++ks) {
      int rec = (ks * 16 + nt) * 64 + lane;
      w0h[m][ks] = ((const f16x8*)(ws + WS_B0H))[rec];
      w0l[m][ks] = ((const f16x8*)(ws + WS_B0L))[rec];
    }
#pragma unroll
    for (int ks = 0; ks < 4; ++ks) {
      int rec = (ks * 16 + nt) * 64 + lane;
      w1h[m][ks] = ((const f16x8*)(ws + WS_B1H))[rec];
      w1l[m][ks] = ((const f16x8*)(ws + WS_B1H + 65536))[rec];
    }
  }
  // Per-lane bias: gates i,f,g,o of cell 4*nt+q
  f32x4 b0v[2], b1v[2];
#pragma unroll
  for (int m = 0; m < 2; ++m) {
    b0v[m] = ((const f32x4*)(ws + WS_BIAS0))[4 * (wave + 8 * m) + q];
    b1v[m] = ((const f32x4*)(ws + WS_BIAS1))[4 * (wave + 8 * m) + q];
  }
  f32x4 z4;
  z4[0] = z4[1] = z4[2] = z4[3] = 0.f;

  // Zero h-exchange (8448 B = 2112 words). Rows 8-15 must stay zero.
  for (int i = tid; i < 2112; i += 512) ((unsigned*)lds)[i] = 0u;

  // x: active lane (q,mcol<8) owns batch (blockIdx*8+mcol), dims 8q..8q+7.
  // Inactive lanes alias batch (mcol&7) — harmless finite data, L1-cached.
  const float* xp =
      x + (size_t)(blockIdx.x * 8 + (mcol & 7)) * (SEQL * 32) + q * 8;
  f32x4 x0a = *(const f32x4*)(xp);
  f32x4 x0b = *(const f32x4*)(xp + 4);
  f16x8 ax = cvt8(x0a, x0b);             // x(0)
  f32x4 xna = *(const f32x4*)(xp + 32);  // x(1) in flight
  f32x4 xnb = *(const f32x4*)(xp + 36);

  const int ard = mcol * ASTR + q * 16;                  // fragment read base
  const int wr0 = mcol * ASTR + (4 * wave + q) * 2;      // h write, ntile0 cell
  const int wr1 = mcol * ASTR + (4 * wave + 32 + q) * 2; // h write, ntile1 cell

  float c1[2] = {0.f, 0.f}, c2[2] = {0.f, 0.f};
  f16x8 ah1[2], ah2[2];
  ah1[0] = ah1[1] = ah2[0] = ah2[1] = zero8();
  __syncthreads();

  // sigma = rcp(1+2^v); tanh = 2*rcp(1+2^v)-1 (weights pre-scaled).
  auto cell = [&](const f32x4& aH, const f32x4& aL, float& c) -> float {
    float p0 = fmaf(aL[0], LO_INV, aH[0]);
    float p1 = fmaf(aL[1], LO_INV, aH[1]);
    float p2 = fmaf(aL[2], LO_INV, aH[2]);
    float p3 = fmaf(aL[3], LO_INV, aH[3]);
    float gi = rcp_(1.f + ex2(p0));
    float gf = rcp_(1.f + ex2(p1));
    float gg = fmaf(2.f, rcp_(1.f + ex2(p2)), -1.f);
    float go = rcp_(1.f + ex2(p3));
    c = fmaf(gf, c, gi * gg);
    float tc = fmaf(2.f, rcp_(1.f + ex2(c * NEG_2L)), -1.f);
    return go * tc;
  };

  // Interval t: G0 = bias0 + W0@[x(t)|h1(t-1)]; G1 = bias1 + W1@[h1(t-1)|h2(t-2)]
  auto iter = [&](int t, int par, bool doL2) {
    const int h1s = par * 128;         // h1(t) slot
    const int h2s = 256 + par * 128;   // h2(t-1) slot
    f32x4 aH0[2], aL0[2], aH1[2], aL1[2];
    // register-only (ax) first: covers post-barrier ds_read latency
    aH0[0] = mfma16(w0h[0][0], ax, b0v[0]);
    aH0[1] = mfma16(w0h[1][0], ax, b0v[1]);
    aL0[0] = mfma16(w0l[0][0], ax, z4);
    aL0[1] = mfma16(w0l[1][0], ax, z4);
    // ah1[0]-dependent
    aH1[0] = mfma16(w1h[0][0], ah1[0], b1v[0]);
    aH1[1] = mfma16(w1h[1][0], ah1[0], b1v[1]);
    aL1[0] = mfma16(w1l[0][0], ah1[0], z4);
    aL1[1] = mfma16(w1l[1][0], ah1[0], z4);
    aH0[0] = mfma16(w0h[0][1], ah1[0], aH0[0]);
    aH0[1] = mfma16(w0h[1][1], ah1[0], aH0[1]);
    aL0[0] = mfma16(w0l[0][1], ah1[0], aL0[0]);
    aL0[1] = mfma16(w0l[1][1], ah1[0], aL0[1]);
    // ah1[1]-dependent
    aH0[0] = mfma16(w0h[0][2], ah1[1], aH0[0]);
    aH0[1] = mfma16(w0h[1][2], ah1[1], aH0[1]);
    aL0[0] = mfma16(w0l[0][2], ah1[1], aL0[0]);
    aL0[1] = mfma16(w0l[1][2], ah1[1], aL0[1]);
    aH1[0] = mfma16(w1h[0][1], ah1[1], aH1[0]);
    aH1[1] = mfma16(w1h[1][1], ah1[1], aH1[1]);
    aL1[0] = mfma16(w1l[0][1], ah1[1], aL1[0]);
    aL1[1] = mfma16(w1l[1][1], ah1[1], aL1[1]);
    // ah2-dependent
    aH1[0] = mfma16(w1h[0][2], ah2[0], aH1[0]);
    aH1[1] = mfma16(w1h[1][2], ah2[0], aH1[1]);
    aL1[0] = mfma16(w1l[0][2], ah2[0], aL1[0]);
    aL1[1] = mfma16(w1l[1][2], ah2[0], aL1[1]);
    aH1[0] = mfma16(w1h[0][3], ah2[1], aH1[0]);
    aH1[1] = mfma16(w1h[1][3], ah2[1], aH1[1]);
    aL1[0] = mfma16(w1l[0][3], ah2[1], aL1[0]);
    aL1[1] = mfma16(w1l[1][3], ah2[1], aL1[1]);
    // Cells (2 per layer per lane); only active lanes publish h
    float h10 = cell(aH0[0], aL0[0], c1[0]);
    float h11 = cell(aH0[1], aL0[1], c1[1]);
    if (act) {
      *(_Float16*)(lds + wr0 + h1s) = (_Float16)h10;
      *(_Float16*)(lds + wr1 + h1s) = (_Float16)h11;
    }
    if (doL2) {
      float h20 = cell(aH1[0], aL1[0], c2[0]);
      float h21 = cell(aH1[1], aL1[1], c2[1]);
      if (act) {
        *(_Float16*)(lds + wr0 + h2s) = (_Float16)h20;
        *(_Float16*)(lds + wr1 + h2s) = (_Float16)h21;
      }
    }
    // x pipeline: consume loads issued one interval ago, issue next
    ax = cvt8(xna, xnb);               // x(t+1)
    int tn = t + 2; if (tn > SEQL - 1) tn = SEQL - 1;
    xna = *(const f32x4*)(xp + tn * 32);
    xnb = *(const f32x4*)(xp + tn * 32 + 4);
    __syncthreads();  // the ONLY barrier per step
    // Reads for t+1 (WAR vs next interval's writes separated by next barrier)
    ah1[0] = *(const f16x8*)(lds + ard + h1s);
    ah1[1] = *(const f16x8*)(lds + ard + h1s + 64);
    ah2[0] = *(const f16x8*)(lds + ard + h2s);
    ah2[1] = *(const f16x8*)(lds + ard + h2s + 64);
  };

  iter(0, 0, false);  // L1(0) only; h2 slot stays zero => h2(-1)=0
#pragma unroll 1
  for (int tp = 0; tp < 127; ++tp) {
    iter(2 * tp + 1, 1, true);
    iter(2 * tp + 2, 0, true);
  }
  iter(255, 1, true);  // L1(255) + L2(254); bottom reads h1(255), h2(254)

  // ---- Epilogue: L2(255) from registers ----
  {
    f32x4 aH[2], aL[2];
    aH[0] = mfma16(w1h[0][0], ah1[0], b1v[0]);
    aH[1] = mfma16(w1h[1][0], ah1[0], b1v[1]);
    aL[0] = mfma16(w1l[0][0], ah1[0], z4);
    aL[1] = mfma16(w1l[1][0], ah1[0], z4);
    aH[0] = mfma16(w1h[0][1], ah1[1], aH[0]);
    aH[1] = mfma16(w1h[1][1], ah1[1], aH[1]);
    aL[0] = mfma16(w1l[0][1], ah1[1], aL[0]);
    aL[1] = mfma16(w1l[1][1], ah1[1], aL[1]);
    aH[0] = mfma16(w1h[0][2], ah2[0], aH[0]);
    aH[1] = mfma16(w1h[1][2], ah2[0], aH[1]);
    aL[0] = mfma16(w1l[0][2], ah2[0], aL[0]);
    aL[1] = mfma16(w1l[1][2], ah2[0], aL[1]);
    aH[0] = mfma16(w1h[0][3], ah2[1], aH[0]);
    aH[1] = mfma16(w1h[1][3], ah2[1], aH[1]);
    aL[0] = mfma16(w1l[0][3], ah2[1], aL[0]);
    aL[1] = mfma16(w1l[1][3], ah2[1], aL[1]);
    float h20 = cell(aH[0], aL[0], c2[0]);
    float h21 = cell(aH[1], aL[1], c2[1]);
    if (act) {
      *(float*)(lds + L_HD + mcol * HDSTR + (4 * wave + q) * 4) = h20;
      *(float*)(lds + L_HD + mcol * HDSTR + (4 * wave + 32 + q) * 4) = h21;
    }
  }
  __syncthreads();

  // ---- Head: f = relu(h2 @ W1.T + b1); out = f @ W2.T + b2 (fp32 h2) ----
  if (tid < 128) {  // 8 outputs per block
    const int s = tid & 15, bo = tid >> 4;
    const float* h2row = (const float*)(lds + L_HD + bo * HDSTR);
    float partial = 0.f;
#pragma unroll
    for (int kk4 = 0; kk4 < 4; ++kk4) {
      int kk = s * 4 + kk4;
      float f = b1[kk];
#pragma unroll
      for (int j = 0; j < 64; j += 4) {
        f32x4 w = *(const f32x4*)(W1 + kk * 64 + j);
        f = fmaf(w[0], h2row[j], f);
        f = fmaf(w[1], h2row[j + 1], f);
        f = fmaf(w[2], h2row[j + 2], f);
        f = fmaf(w[3], h2row[j + 3], f);
      }
      f = fmaxf(f, 0.f);
      partial = fmaf(f, W2[kk], partial);
    }
    partial += __shfl_xor(partial, 8, 64);
    partial += __shfl_xor(partial, 4, 64);
    partial += __shfl_xor(partial, 2, 64);
    partial += __shfl_xor(partial, 1, 64);
    if (s == 0) out[blockIdx.x * 8 + bo] = partial + b2[0];
  }
}

extern "C" void kernel_launch(void* const* d_in, const int* in_sizes, int n_in,
                              void* d_out, int out_size, void* d_ws, size_t ws_size,
                              hipStream_t stream) {
  const float* x    = (const float*)d_in[0];
  const float* Wih0 = (const float*)d_in[1];
  const float* Whh0 = (const float*)d_in[2];
  const float* bih0 = (const float*)d_in[3];
  const float* bhh0 = (const float*)d_in[4];
  const float* Wih1 = (const float*)d_in[5];
  const float* Whh1 = (const float*)d_in[6];
  const float* bih1 = (const float*)d_in[7];
  const float* bhh1 = (const float*)d_in[8];
  const float* W1   = (const float*)d_in[9];
  const float* b1   = (const float*)d_in[10];
  const float* W2   = (const float*)d_in[11];
  const float* b2   = (const float*)d_in[12];
  unsigned char* ws = (unsigned char*)d_ws;
  float* out = (float*)d_out;

  prep<<<(57856 + 255) / 256, 256, 0, stream>>>(Wih0, Whh0, bih0, bhh0,
                                                Wih1, Whh1, bih1, bhh1, ws);
  lstm_mfma11<<<512, 512, 0, stream>>>(x, ws, W1, b1, W2, b2, out);
}

// Round 7
// 455.609 us; speedup vs baseline: 6.0848x; 1.4435x over previous
//
#include <hip/hip_runtime.h>
#include <cstdint>

typedef __attribute__((ext_vector_type(8))) _Float16 f16x8;
typedef __attribute__((ext_vector_type(4))) float f32x4;

#define SEQL 256

// ws byte offsets (prep output)
#define WS_B0H   0        // [3 kstep][16 ntile][64 lane][8] f16 = 49152 B
#define WS_B0L   49152    // lo pre-scaled x2048
#define WS_B1H   98304    // [4][16][64][8] f16 hi = 65536 B, then lo contiguous
#define WS_BIAS0 229376   // 256 f32, index = cell*4+gate, pre-scaled
#define WS_BIAS1 230400

// LDS: h-exchange only (x lives in registers). Row (per batch col) = 528 B
// = 132 words (132 mod 32 = 4 -> 64-lane b128 reads hit each 4-bank window
// with exactly 8 lanes = minimum).  h1_0@0(128B) h1_1@128 h2_0@256 h2_1@384
#define ASTR 528
#define L_HD 8448         // head exchange: 16 rows x 272 B
#define HDSTR 272
#define LDS_TOTAL 12800

#define NEG_L   -1.4426950408889634f   // -log2(e)
#define NEG_2L  -2.8853900817779268f   // -2*log2(e)
#define LO_SCALE 2048.0f
#define LO_INV   4.8828125e-4f         // 1/2048

__device__ __forceinline__ float ex2(float x) { return __builtin_amdgcn_exp2f(x); }
__device__ __forceinline__ float rcp_(float x) { return __builtin_amdgcn_rcpf(x); }
__device__ __forceinline__ f32x4 mfma16(f16x8 a, f16x8 b, f32x4 c) {
  return __builtin_amdgcn_mfma_f32_16x16x32_f16(a, b, c, 0, 0, 0);
}
__device__ __forceinline__ f16x8 zero8() {
  f16x8 z;
#pragma unroll
  for (int i = 0; i < 8; ++i) z[i] = (_Float16)0.f;
  return z;
}
__device__ __forceinline__ f16x8 cvt8(f32x4 a, f32x4 b) {
  f16x8 r;
#pragma unroll
  for (int j = 0; j < 4; ++j) r[j] = (_Float16)a[j];
#pragma unroll
  for (int j = 0; j < 4; ++j) r[4 + j] = (_Float16)b[j];
  return r;
}
__device__ __forceinline__ unsigned f16bits(float h) {
  _Float16 hf = (_Float16)h;
  unsigned short us;
  __builtin_memcpy(&us, &hf, 2);
  return (unsigned)us;
}

// h storage K-permutation: memory position p holds cell cp(p).
// (packed writes store [c0,c2,c1,c3] per 4-cell group)
__device__ __forceinline__ int cp(int p) {
  return (p & ~3) | ((p & 1) << 1) | ((p >> 1) & 1);
}

// Pack weights into MFMA fragment order (A-operand), f16 hi + f16 lo(x2048),
// pre-scaled by -log2e (i,f,o) / -2log2e (g). h-cell K-positions permuted by
// cp() to match the packed h-write order.
__global__ __launch_bounds__(256) void prep(
    const float* __restrict__ Wih0, const float* __restrict__ Whh0,
    const float* __restrict__ bih0, const float* __restrict__ bhh0,
    const float* __restrict__ Wih1, const float* __restrict__ Whh1,
    const float* __restrict__ bih1, const float* __restrict__ bhh1,
    unsigned char* __restrict__ ws) {
  int e = blockIdx.x * 256 + threadIdx.x;
  if (e < 24576) {  // B0: K=96 = [x(32)|h1(64)]
    int j = e & 7, lane = (e >> 3) & 63, nt = (e >> 9) & 15, ks = e >> 13;
    int kdim = ks * 32 + (lane >> 4) * 8 + j;
    int col = nt * 16 + (lane & 15);   // gate-row index of the A-operand
    int ko = col >> 2, g = col & 3;
    float w = (kdim < 32) ? Wih0[(g * 64 + ko) * 32 + kdim]
                          : Whh0[(g * 64 + ko) * 64 + cp(kdim - 32)];
    w *= (g == 2) ? NEG_2L : NEG_L;
    _Float16 hi = (_Float16)w;
    _Float16 lo = (_Float16)((w - (float)hi) * LO_SCALE);
    ((_Float16*)(ws + WS_B0H))[e] = hi;
    ((_Float16*)(ws + WS_B0L))[e] = lo;
  } else if (e < 57344) {  // B1: K=128 = [h1(64)|h2(64)]
    int r = e - 24576;
    int j = r & 7, lane = (r >> 3) & 63, nt = (r >> 9) & 15, ks = r >> 13;
    int kdim = ks * 32 + (lane >> 4) * 8 + j;
    int col = nt * 16 + (lane & 15);
    int ko = col >> 2, g = col & 3;
    float w = (kdim < 64) ? Wih1[(g * 64 + ko) * 64 + cp(kdim)]
                          : Whh1[(g * 64 + ko) * 64 + cp(kdim - 64)];
    w *= (g == 2) ? NEG_2L : NEG_L;
    _Float16 hi = (_Float16)w;
    _Float16 lo = (_Float16)((w - (float)hi) * LO_SCALE);
    ((_Float16*)(ws + WS_B1H))[r] = hi;
    ((_Float16*)(ws + WS_B1H + 65536))[r] = lo;
  } else if (e < 57856) {  // biases (pre-scaled, fp32)
    int r = e - 57344;
    int col = r & 255, ko = col >> 2, g = col & 3;
    float v = (r < 256) ? bih0[g * 64 + ko] + bhh0[g * 64 + ko]
                        : bih1[g * 64 + ko] + bhh1[g * 64 + ko];
    v *= (g == 2) ? NEG_2L : NEG_L;
    ((float*)(ws + (r < 256 ? WS_BIAS0 : WS_BIAS1)))[col] = v;
  }
}

// v12 = v6 (16 waves x 1 ntile, single barrier, 326us) with the LDS pipe cut:
//  - x direct-from-global per lane (VMEM pipe, 1-interval reg prefetch);
//    removes 16 ds_reads + all x staging writes per interval
//  - packed h-writes: shfl_xor(32) pairs cells in-lane, lanes<32 write one
//    b32 (2-way aliasing = free) instead of 64 scattered b16 (the measured
//    conflict source); K-order permutation absorbed in prep
//  - cell transcendental fusion: 8 trans/cell instead of 10
__global__ __launch_bounds__(1024, 4) void lstm_mfma12(
    const float* __restrict__ x, const unsigned char* __restrict__ ws,
    const float* __restrict__ W1, const float* __restrict__ b1,
    const float* __restrict__ W2, const float* __restrict__ b2,
    float* __restrict__ out) {
  __shared__ __align__(16) unsigned char lds[LDS_TOTAL];
  const int tid = threadIdx.x;
  const int lane = tid & 63, wave = tid >> 6;  // 16 waves, 1 ntile each
  const int q = lane >> 4, mcol = lane & 15;

  // ---- Weight fragments -> registers (loop-invariant, A-operand) ----
  f16x8 b0h[3], b0l[3], b1h[4], b1l[4];
#pragma unroll
  for (int ks = 0; ks < 3; ++ks) {
    int rec = (ks * 16 + wave) * 64 + lane;
    b0h[ks] = ((const f16x8*)(ws + WS_B0H))[rec];
    b0l[ks] = ((const f16x8*)(ws + WS_B0L))[rec];
  }
#pragma unroll
  for (int ks = 0; ks < 4; ++ks) {
    int rec = (ks * 16 + wave) * 64 + lane;
    b1h[ks] = ((const f16x8*)(ws + WS_B1H))[rec];
    b1l[ks] = ((const f16x8*)(ws + WS_B1H + 65536))[rec];
  }
  // Per-lane bias: gates i,f,g,o of cell wave*4+q
  const f32x4 bias0v = ((const f32x4*)(ws + WS_BIAS0))[wave * 4 + q];
  const f32x4 bias1v = ((const f32x4*)(ws + WS_BIAS1))[wave * 4 + q];
  f32x4 z4;
  z4[0] = z4[1] = z4[2] = z4[3] = 0.f;

  // Zero h-exchange (8448 B = 2112 words): h1(-1)=h2(-1)=h2(-2)=0
  for (int i = tid; i < 2112; i += 1024) ((unsigned*)lds)[i] = 0u;

  // x: lane (q,mcol) owns batch (blockIdx*16+mcol), dims 8q..8q+7 (32 B).
  // All 16 waves load the same 2KB/t working set -> L1 broadcast.
  const float* xp = x + (size_t)(blockIdx.x * 16 + mcol) * (SEQL * 32) + q * 8;
  f16x8 ax = cvt8(*(const f32x4*)(xp), *(const f32x4*)(xp + 4));  // x(0)
  f32x4 xa = *(const f32x4*)(xp + 32);  // x(1) lo half, 1 interval in flight

  const int ard = mcol * ASTR + q * 16;  // fragment read base

  float c1 = 0.f, c2 = 0.f, h2f = 0.f;
  f16x8 ah1[2], ah2[2];
  ah1[0] = ah1[1] = ah2[0] = ah2[1] = zero8();
  __syncthreads();

  // Fused cell: sigma/tanh via 2^v with combined reciprocals (8 trans).
  // gi*gg = (1-B)/((1+A)(1+B)); go*tanh(c) = (1-D)/((1+C)(1+D)).
  // D exponent clamped (<=2^100) so (1-D)*rcp(...) never hits inf*0.
  auto cell = [&](const f32x4& aH, const f32x4& aL, float& c) -> float {
    float p0 = fmaf(aL[0], LO_INV, aH[0]);   // i (pre-scaled by -log2e)
    float p1 = fmaf(aL[1], LO_INV, aH[1]);   // f
    float p2 = fmaf(aL[2], LO_INV, aH[2]);   // g (pre-scaled by -2log2e)
    float p3 = fmaf(aL[3], LO_INV, aH[3]);   // o
    float A = ex2(p0), F = ex2(p1), B = ex2(p2), C = ex2(p3);
    float ig = (1.f - B) * rcp_((1.f + A) * (1.f + B));   // gi*gg
    float gf = rcp_(1.f + F);
    c = fmaf(gf, c, ig);
    float D = ex2(fminf(c * NEG_2L, 100.f));
    return (1.f - D) * rcp_((1.f + C) * (1.f + D));       // go*tanh(c)
  };

  // Packed h write: pair own cell (4w+q) with partner (4w+q+2) from lane+32,
  // lanes<32 write one b32. Memory order [c0,c2,c1,c3] == cp().
  auto hwrite = [&](float h, int slot) {
    int hb = (int)f16bits(h);
    int partner = __shfl_xor(hb, 32, 64);
    if (lane < 32) {
      unsigned v = ((unsigned)hb & 0xffffu) | ((unsigned)partner << 16);
      *(unsigned*)(lds + mcol * ASTR + slot + wave * 8 + q * 4) = v;
    }
  };

  // Interval t: G0 = bias0 + W0@[x(t)|h1(t-1)]; G1 = bias1 + W1@[h1(t-1)|h2(t-2)]
  auto iter = [&](int t, int par, bool doL2) {
    const int h1s = par * 128;         // h1(t) slot
    const int h2s = 256 + par * 128;   // h2(t-1) slot
    const int tn1 = (t + 1 < SEQL) ? t + 1 : SEQL - 1;
    const int tn2 = (t + 2 < SEQL) ? t + 2 : SEQL - 1;
    // issue x(t+1) hi-half early: consumed at interval end (L1-hot line)
    f32x4 xb = *(const f32x4*)(xp + tn1 * 32 + 4);

    f32x4 aH0, aL0, aH1, aL1;
    // register-only (ax) first: covers post-barrier ds_read latency
    aH0 = mfma16(b0h[0], ax, bias0v);
    aL0 = mfma16(b0l[0], ax, z4);
    aH1 = mfma16(b1h[0], ah1[0], bias1v);
    aL1 = mfma16(b1l[0], ah1[0], z4);
    aH0 = mfma16(b0h[1], ah1[0], aH0);
    aL0 = mfma16(b0l[1], ah1[0], aL0);
    aH1 = mfma16(b1h[1], ah1[1], aH1);
    aL1 = mfma16(b1l[1], ah1[1], aL1);
    aH0 = mfma16(b0h[2], ah1[1], aH0);
    aL0 = mfma16(b0l[2], ah1[1], aL0);
    aH1 = mfma16(b1h[2], ah2[0], aH1);
    aL1 = mfma16(b1l[2], ah2[0], aL1);
    aH1 = mfma16(b1h[3], ah2[1], aH1);
    aL1 = mfma16(b1l[3], ah2[1], aL1);

    // Cell 1 -> h1(t)
    float h1 = cell(aH0, aL0, c1);
    hwrite(h1, h1s);
    // Cell 2 -> h2(t-1)
    if (doL2) {
      float h2 = cell(aH1, aL1, c2);
      hwrite(h2, h2s);
    }
    // x pipeline: consume (xa,xb), issue lo-half of x(t+2)
    ax = cvt8(xa, xb);
    xa = *(const f32x4*)(xp + tn2 * 32);
    __syncthreads();  // the ONLY barrier per step
    // Reads for t+1 (WAR vs next interval's writes separated by next barrier)
    ah1[0] = *(const f16x8*)(lds + ard + h1s);
    ah1[1] = *(const f16x8*)(lds + ard + h1s + 64);
    ah2[0] = *(const f16x8*)(lds + ard + h2s);
    ah2[1] = *(const f16x8*)(lds + ard + h2s + 64);
  };

  iter(0, 0, false);  // L1(0) only; h2 slot stays zero => h2(-1)=0
#pragma unroll 1
  for (int tp = 0; tp < 127; ++tp) {
    iter(2 * tp + 1, 1, true);
    iter(2 * tp + 2, 0, true);
  }
  iter(255, 1, true);  // L1(255) + L2(254); bottom reads h1(255), h2(254)

  // ---- Epilogue: L2(255) -> h2f ----
  {
    f32x4 aH = mfma16(b1h[0], ah1[0], bias1v);
    f32x4 aL = mfma16(b1l[0], ah1[0], z4);
    aH = mfma16(b1h[1], ah1[1], aH);
    aL = mfma16(b1l[1], ah1[1], aL);
#pragma unroll
    for (int ks = 0; ks < 2; ++ks) {
      aH = mfma16(b1h[ks + 2], ah2[ks], aH);
      aL = mfma16(b1l[ks + 2], ah2[ks], aL);
    }
    h2f = cell(aH, aL, c2);
  }

  // ---- Head: f = relu(h2 @ W1.T + b1); out = f @ W2.T + b2 (fp32 h2) ----
  __syncthreads();
  *(float*)(lds + L_HD + mcol * HDSTR + (wave * 4 + q) * 4) = h2f;
  __syncthreads();
  if (tid < 256) {
    const int s = tid & 15, bo = tid >> 4;
    const float* h2row = (const float*)(lds + L_HD + bo * HDSTR);
    float partial = 0.f;
#pragma unroll
    for (int kk4 = 0; kk4 < 4; ++kk4) {
      int kk = s * 4 + kk4;
      float f = b1[kk];
#pragma unroll
      for (int j = 0; j < 64; j += 4) {
        f32x4 w = *(const f32x4*)(W1 + kk * 64 + j);
        f = fmaf(w[0], h2row[j], f);
        f = fmaf(w[1], h2row[j + 1], f);
        f = fmaf(w[2], h2row[j + 2], f);
        f = fmaf(w[3], h2row[j + 3], f);
      }
      f = fmaxf(f, 0.f);
      partial = fmaf(f, W2[kk], partial);
    }
    partial += __shfl_xor(partial, 8, 64);
    partial += __shfl_xor(partial, 4, 64);
    partial += __shfl_xor(partial, 2, 64);
    partial += __shfl_xor(partial, 1, 64);
    if (s == 0) out[blockIdx.x * 16 + bo] = partial + b2[0];
  }
}

extern "C" void kernel_launch(void* const* d_in, const int* in_sizes, int n_in,
                              void* d_out, int out_size, void* d_ws, size_t ws_size,
                              hipStream_t stream) {
  const float* x    = (const float*)d_in[0];
  const float* Wih0 = (const float*)d_in[1];
  const float* Whh0 = (const float*)d_in[2];
  const float* bih0 = (const float*)d_in[3];
  const float* bhh0 = (const float*)d_in[4];
  const float* Wih1 = (const float*)d_in[5];
  const float* Whh1 = (const float*)d_in[6];
  const float* bih1 = (const float*)d_in[7];
  const float* bhh1 = (const float*)d_in[8];
  const float* W1   = (const float*)d_in[9];
  const float* b1   = (const float*)d_in[10];
  const float* W2   = (const float*)d_in[11];
  const float* b2   = (const float*)d_in[12];
  unsigned char* ws = (unsigned char*)d_ws;
  float* out = (float*)d_out;

  prep<<<(57856 + 255) / 256, 256, 0, stream>>>(Wih0, Whh0, bih0, bhh0,
                                                Wih1, Whh1, bih1, bhh1, ws);
  lstm_mfma12<<<256, 1024, 0, stream>>>(x, ws, W1, b1, W2, b2, out);
}